// Round 10
// baseline (632.722 us; speedup 1.0000x reference)
//
#include <hip/hip_runtime.h>
#include <hip/hip_bf16.h>
#include <stdint.h>
#include <stddef.h>

#define NN 8192
#define DD 128
#define TILE_R 16
#define TILE_C 1024
#define PADW 1032   // LDS row stride (bf16): 2064 B
#define PANELS 8    // j-panels (grid.x)

typedef __attribute__((ext_vector_type(8))) short bf16x8;
typedef __attribute__((ext_vector_type(4))) float f32x4;

static __device__ __forceinline__ unsigned short f2bf(float x) {
  __hip_bfloat16 h = __float2bfloat16(x);
  return *(unsigned short*)&h;
}

// ---------------------------------------------------------------------------
// Kernel 1: row-normalize features (fp32) and cast to bf16. One wave per row.
// ---------------------------------------------------------------------------
__global__ __launch_bounds__(256) void normalize_kernel(
    const float* __restrict__ f, __hip_bfloat16* __restrict__ fn) {
  const int wave = threadIdx.x >> 6;
  const int lane = threadIdx.x & 63;
  const int row = blockIdx.x * 4 + wave;
  const float2 v = ((const float2*)(f + (size_t)row * DD))[lane];
  float ss = v.x * v.x + v.y * v.y;
#pragma unroll
  for (int m = 1; m < 64; m <<= 1) ss += __shfl_xor(ss, m, 64);
  const float inv = 1.0f / fmaxf(sqrtf(ss), 1e-8f);
  __hip_bfloat162 o;
  o.x = __float2bfloat16(v.x * inv);
  o.y = __float2bfloat16(v.y * inv);
  ((__hip_bfloat162*)(fn + (size_t)row * DD))[lane] = o;
}

// ---------------------------------------------------------------------------
// Kernel 2: WIDE tile — 16 rows x 1024 cols per 256-thread block.
// Rationale (r10 theory): MFMA cost per output element is shape-invariant,
// but mask reads become 4 KB-contiguous per row per array (vs 512 B at
// 128-col tiles), and phase 3 is arranged so ONE wave reads a row's full
// 4 KB in 4 back-to-back 1 KB wave-loads -> DRAM page locality restored.
//   Phase 1: GEMM. Wave w covers cols [w*256, w*256+256): acc[16] f32x4.
//     Fragment (nt,r): i = I0g + l16, j = J0w + nt*16 + quad*4 + r.
//   Phase 2: exp(sim/T) -> LDS bf16 [16][1032] (33 KB -> 4 blocks/CU).
//   Phase 3: wave w owns rows [w*4, w*4+4); per row, 4 passes of 64xint4
//     (1 KB contiguous wave-loads); lane-local partials, one deferred
//     64-lane butterfly, 3 scalar stores per row into 8-panel arrays.
// ---------------------------------------------------------------------------
template <bool DIAG, bool ATOMIC>
static __device__ __forceinline__ void tile_body(
    const __hip_bfloat16* __restrict__ fn,
    const int* __restrict__ pmask, const int* __restrict__ nmask,
    float* __restrict__ pP, float* __restrict__ nP, float* __restrict__ cP,
    __hip_bfloat16* __restrict__ sim) {
  const int tid = threadIdx.x;
  const int lane = tid & 63;
  const int quad = lane >> 4;
  const int l16 = lane & 15;
  const int w = tid >> 6;  // wave 0..3

  const int I0g = blockIdx.y * TILE_R;
  const int J0g = blockIdx.x * TILE_C;
  const int J0w = J0g + w * 256;

  // ---- Phase 1: GEMM ----
  f32x4 acc[16] = {};
#pragma unroll
  for (int kt = 0; kt < 4; ++kt) {
    const int ko = kt * 32 + quad * 8;
    const bf16x8 aF = *(const bf16x8*)(fn + (size_t)(I0g + l16) * DD + ko);
#pragma unroll
    for (int nt = 0; nt < 16; ++nt) {
      const bf16x8 bF =
          *(const bf16x8*)(fn + (size_t)(J0w + nt * 16 + l16) * DD + ko);
      acc[nt] = __builtin_amdgcn_mfma_f32_16x16x32_bf16(
          bF, aF, acc[nt], 0, 0, 0);  // SWAPPED operands
    }
  }

  // ---- Phase 2: exp -> LDS (bf16) ----
  const float tinv = 1.0f / 0.07f;
#pragma unroll
  for (int nt = 0; nt < 16; ++nt) {
    const int col = w * 256 + nt * 16 + quad * 4;
    ushort4 w4;
    w4.x = f2bf(__expf(acc[nt][0] * tinv));
    w4.y = f2bf(__expf(acc[nt][1] * tinv));
    w4.z = f2bf(__expf(acc[nt][2] * tinv));
    w4.w = f2bf(__expf(acc[nt][3] * tinv));
    *(ushort4*)(sim + (size_t)l16 * PADW + col) = w4;
  }
  __syncthreads();

  // ---- Phase 3: wave-sequential 4 KB row streams ----
  float accP[4], accQ[4], accC[4];
#pragma unroll
  for (int rr = 0; rr < 4; ++rr) {
    const int row = w * 4 + rr;
    const int iG = I0g + row;
    const int* pr = pmask + (size_t)iG * NN + J0g;
    const int* nr = nmask + (size_t)iG * NN + J0g;
    float p = 0.f, q = 0.f;
    int c = 0;
#pragma unroll
    for (int pass = 0; pass < 4; ++pass) {
      const int jb = pass * 256 + lane * 4;
      const int4 pm4 = *(const int4*)(pr + jb);
      const int4 nm4 = *(const int4*)(nr + jb);
      const ushort4 e4 = *(const ushort4*)(sim + (size_t)row * PADW + jb);
      const int dj = DIAG ? (iG - (J0g + jb)) : -1;
#pragma unroll
      for (int r = 0; r < 4; ++r) {
        int pm = (&pm4.x)[r];
        int nm = (&nm4.x)[r];
        if (DIAG) {
          if (r == dj) { pm = 0; nm = 0; }  // zero self-contrast
        }
        const float e = __uint_as_float(((unsigned int)(&e4.x)[r]) << 16);
        p = fmaf(e, (float)pm, p);
        q = fmaf(e, (float)nm, q);
        c += pm;
      }
    }
    accP[rr] = p; accQ[rr] = q; accC[rr] = (float)c;
  }

  // ---- deferred 64-lane butterfly (12 independent chains) ----
#pragma unroll
  for (int m = 1; m < 64; m <<= 1) {
#pragma unroll
    for (int rr = 0; rr < 4; ++rr) {
      accP[rr] += __shfl_xor(accP[rr], m, 64);
      accQ[rr] += __shfl_xor(accQ[rr], m, 64);
      accC[rr] += __shfl_xor(accC[rr], m, 64);
    }
  }
#pragma unroll
  for (int rr = 0; rr < 4; ++rr) {
    const int iG = I0g + w * 4 + rr;
    if (ATOMIC) {
      if (lane == 0)      atomicAdd(&pP[iG], accP[rr]);
      else if (lane == 1) atomicAdd(&nP[iG], accQ[rr]);
      else if (lane == 2) atomicAdd(&cP[iG], accC[rr]);
    } else {
      const size_t po = (size_t)blockIdx.x * NN + iG;
      if (lane == 0)      pP[po] = accP[rr];
      else if (lane == 1) nP[po] = accQ[rr];
      else if (lane == 2) cP[po] = accC[rr];
    }
  }
}

template <bool ATOMIC>
__global__ __launch_bounds__(256, 4) void ssnt_main(
    const __hip_bfloat16* __restrict__ fn,
    const int* __restrict__ pmask,
    const int* __restrict__ nmask,
    float* __restrict__ pP, float* __restrict__ nP, float* __restrict__ cP) {
  __shared__ __hip_bfloat16 sim[TILE_R * PADW];  // 33 KB -> 4 blocks/CU
  // block holds the diagonal iff its 16-row band lies in its 1024-col panel
  if ((blockIdx.y >> 6) == blockIdx.x)
    tile_body<true, ATOMIC>(fn, pmask, nmask, pP, nP, cP, sim);
  else
    tile_body<false, ATOMIC>(fn, pmask, nmask, pP, nP, cP, sim);
}

// ---------------------------------------------------------------------------
// Kernel 3a: reduce panels per row, per-row loss term, block sum -> blkSum[32]
// ---------------------------------------------------------------------------
__global__ __launch_bounds__(256) void finalize1(
    const float* __restrict__ pP, const float* __restrict__ nP,
    const float* __restrict__ cP, int panels, float* __restrict__ blkSum) {
  const int r = blockIdx.x * 256 + threadIdx.x;
  float p = 0.f, q = 0.f, c = 0.f;
  for (int k = 0; k < panels; ++k) {
    p += pP[(size_t)k * NN + r];
    q += nP[(size_t)k * NN + r];
    c += cP[(size_t)k * NN + r];
  }
  float s = logf(p / (p + q)) / c;
#pragma unroll
  for (int m = 1; m < 64; m <<= 1) s += __shfl_xor(s, m, 64);
  __shared__ float ws4[4];
  if ((threadIdx.x & 63) == 0) ws4[threadIdx.x >> 6] = s;
  __syncthreads();
  if (threadIdx.x == 0)
    blkSum[blockIdx.x] = ws4[0] + ws4[1] + ws4[2] + ws4[3];
}

// Kernel 3b: final 32-value sum -> loss
__global__ void finalize2(const float* __restrict__ blkSum,
                          float* __restrict__ out) {
  float s = (threadIdx.x < NN / 256) ? blkSum[threadIdx.x] : 0.f;
#pragma unroll
  for (int m = 1; m < 64; m <<= 1) s += __shfl_xor(s, m, 64);
  if (threadIdx.x == 0) out[0] = -s / (float)NN;
}

extern "C" void kernel_launch(void* const* d_in, const int* in_sizes, int n_in,
                              void* d_out, int out_size, void* d_ws, size_t ws_size,
                              hipStream_t stream) {
  const float* features = (const float*)d_in[0];
  const int* pmask = (const int*)d_in[1];
  const int* nmask = (const int*)d_in[2];
  float* out = (float*)d_out;

  char* ws = (char*)d_ws;
  __hip_bfloat16* fn = (__hip_bfloat16*)ws;  // 2 MB
  float* base = (float*)(ws + (size_t)NN * DD * sizeof(__hip_bfloat16));

  normalize_kernel<<<NN / 4, 256, 0, stream>>>(features, fn);

  const size_t needPanels =
      (size_t)NN * DD * 2 + 3ull * PANELS * NN * sizeof(float) + 256;
  if (ws_size >= needPanels) {
    // panel path: atomic-free, no memset
    float* pP = base;
    float* nP = pP + (size_t)PANELS * NN;
    float* cP = nP + (size_t)PANELS * NN;
    float* blkSum = cP + (size_t)PANELS * NN;
    ssnt_main<false><<<dim3(NN / TILE_C, NN / TILE_R), 256, 0, stream>>>(
        fn, pmask, nmask, pP, nP, cP);
    finalize1<<<NN / 256, 256, 0, stream>>>(pP, nP, cP, PANELS, blkSum);
    finalize2<<<1, 64, 0, stream>>>(blkSum, out);
  } else {
    // fallback: atomic accumulation into [NN] arrays
    float* pP = base;
    float* nP = pP + NN;
    float* cP = nP + NN;
    float* blkSum = cP + NN;
    hipMemsetAsync(pP, 0, 3 * (size_t)NN * sizeof(float), stream);
    ssnt_main<true><<<dim3(NN / TILE_C, NN / TILE_R), 256, 0, stream>>>(
        fn, pmask, nmask, pP, nP, cP);
    finalize1<<<NN / 256, 256, 0, stream>>>(pP, nP, cP, 1, blkSum);
    finalize2<<<1, 64, 0, stream>>>(blkSum, out);
  }
}